// Round 3
// baseline (246.486 us; speedup 1.0000x reference)
//
#include <hip/hip_runtime.h>
#include <cstddef>
#include <cmath>

// ---------------------------------------------------------------------------
// SWGAT layer:
//   z = h @ W_fc.T                       [N,128]
//   e = leaky_relu(a1[src] + a2[dst]);  e==0 -> -1000
//   segment softmax over dst, out[w] = sum alpha * z[src]
// R9: attack the 70us fused gemm+scatter (MfmaUtil 3.4%, VALU 4.8%, HBM 20%,
//     Occ 33% -> pure latency-bound). 64KB LDS / 8-wave blocks capped
//     residency at 2 blocks/CU. Now: 256-thr 4-wave blocks, 128-row tile,
//     B staged as two 32KB col-halves (phase loop, A re-read hits L2/L3),
//     launch_bounds(256,5) -> 5 blocks/CU = 20 waves. Scatter grid-strided
//     (4 edges/thr, 489 blocks); 1271 total blocks <= 1280 slots = single
//     round, scatter fully co-resident under gemm.
// ---------------------------------------------------------------------------

#define IN_DIM  256
#define OUT_DIM 128
#define CAP     64      // max edges kept per dst (Poisson(10) => max deg ~30)

typedef _Float16 half2_t __attribute__((ext_vector_type(2)));
typedef _Float16 half8_t __attribute__((ext_vector_type(8)));
typedef float    f32x4   __attribute__((ext_vector_type(4)));

// --- K0: convert W_fc fp32 -> f16 (swizzled granules) + zero cnt ------------
// granule g = n*32 + (kb ^ (n&7)) holds wfc[n][kb*8 .. kb*8+7]
__global__ __launch_bounds__(256) void wconv_kernel(const float* __restrict__ wfc,
                                                    _Float16* __restrict__ wh,
                                                    int* __restrict__ cnt, int NW) {
    int idx = blockIdx.x * 256 + threadIdx.x;
    if (idx < (IN_DIM / 8) * OUT_DIM) {     // 4096 granules
        int n  = idx >> 5;
        int kb = idx & 31;
        const float* p = wfc + (size_t)n * IN_DIM + kb * 8;
        float4 v0 = *(const float4*)p;
        float4 v1 = *(const float4*)(p + 4);
        half8_t hv = {(_Float16)v0.x, (_Float16)v0.y, (_Float16)v0.z, (_Float16)v0.w,
                      (_Float16)v1.x, (_Float16)v1.y, (_Float16)v1.z, (_Float16)v1.w};
        *(half8_t*)&wh[(size_t)(n * 32 + (kb ^ (n & 7))) * 8] = hv;
    }
    if (idx < NW) cnt[idx] = 0;
}

// --- K1: fused gemm + scatter dispatch --------------------------------------
// Blocks [0, GB): 256 thr = 4 waves, tile 128 rows x 128 cols. B staged in
//   two 32KB col-half phases into one buffer; wave w owns rows {w*16..+15}
//   and {64+w*16..+15}. A re-read in phase 1 is L2/L3-hot. a1/a2 partial
//   attn dots accumulate across phases in registers, stored once.
// Blocks [GB, GB+SB): scatter, 4 edges/thread grid-stride (no LDS use).
__global__ __launch_bounds__(256, 5) void gemm_scatter_kernel(
        const float* __restrict__ h, const _Float16* __restrict__ wh,
        const float* __restrict__ wattn, _Float16* __restrict__ zh,
        float* __restrict__ a1, float* __restrict__ a2, int M, int GB,
        const int* __restrict__ src, const int* __restrict__ dst,
        int* __restrict__ cnt, int* __restrict__ bucket, int E) {
    __shared__ _Float16 Bs[64 * IN_DIM];   // 32 KB (one col-half of W)

    const int t = threadIdx.x;

    if (blockIdx.x >= GB) {
        // ---- scatter block: 4 edges per thread, coalesced strided ----
        int base = (blockIdx.x - GB) * 1024;
#pragma unroll
        for (int k = 0; k < 4; ++k) {
            int i = base + k * 256 + t;
            if (i < E) {
                int s = src[i];
                int d = dst[i];
                int pos = atomicAdd(&cnt[d], 1);
                if (pos < CAP)                  // overflow guard (never hit here)
                    bucket[(size_t)d * CAP + pos] = s;
            }
        }
        return;
    }

    // ---- gemm block ----
    const int lane = t & 63;
    const int w    = t >> 6;          // 0..3
    const int quad = lane >> 4;       // 0..3
    const int l15  = lane & 15;
    const int m0   = blockIdx.x * 128;

    // lane's two A rows (clamped; OOB rows computed but never stored)
    const int lrow0 = w * 16 + l15;
    const int lrow1 = 64 + w * 16 + l15;
    const int g0 = (m0 + lrow0 < M) ? (m0 + lrow0) : (M - 1);
    const int g1 = (m0 + lrow1 < M) ? (m0 + lrow1) : (M - 1);
    const float* arow0 = h + (size_t)g0 * IN_DIM;
    const float* arow1 = h + (size_t)g1 * IN_DIM;

    float ps1[2][4];   // a1-partials per (row-set, r), accumulated over phases
    float ps2[2][4];
#pragma unroll
    for (int s = 0; s < 2; ++s)
#pragma unroll
        for (int r = 0; r < 4; ++r) { ps1[s][r] = 0.f; ps2[s][r] = 0.f; }

#pragma unroll
    for (int p = 0; p < 2; ++p) {
        // ---- stage this col-half of B: granules [p*2048, p*2048+2048) ----
        if (p) __syncthreads();               // waves done reading Bs phase 0
#pragma unroll
        for (int i = 0; i < 8; ++i) {
            int idx = t + i * 256;            // local granule 0..2047
            *(half8_t*)&Bs[(size_t)idx * 8] =
                *(const half8_t*)&wh[(size_t)(p * 2048 + idx) * 8];
        }
        __syncthreads();

        f32x4 acc[2][4] = {};   // [row-set][ni]

#pragma unroll
        for (int kc = 0; kc < 8; ++kc) {
            // A-frags straight from global: 8 fp32 = 32 B contiguous per lane
            float4 u0 = *(const float4*)(arow0 + kc * 32 + quad * 8);
            float4 u1 = *(const float4*)(arow0 + kc * 32 + quad * 8 + 4);
            float4 v0 = *(const float4*)(arow1 + kc * 32 + quad * 8);
            float4 v1 = *(const float4*)(arow1 + kc * 32 + quad * 8 + 4);
            half8_t a0 = {(_Float16)u0.x, (_Float16)u0.y, (_Float16)u0.z, (_Float16)u0.w,
                          (_Float16)u1.x, (_Float16)u1.y, (_Float16)u1.z, (_Float16)u1.w};
            half8_t a1f = {(_Float16)v0.x, (_Float16)v0.y, (_Float16)v0.z, (_Float16)v0.w,
                           (_Float16)v1.x, (_Float16)v1.y, (_Float16)v1.z, (_Float16)v1.w};
#pragma unroll
            for (int ni = 0; ni < 4; ++ni) {
                int nl = ni * 16 + l15;                  // local col 0..63
                int g  = (kc * 4 + quad) ^ (nl & 7);
                half8_t b = *(const half8_t*)&Bs[(size_t)(nl * 32 + g) * 8];
                acc[0][ni] = __builtin_amdgcn_mfma_f32_16x16x32_f16(a0,  b, acc[0][ni], 0, 0, 0);
                acc[1][ni] = __builtin_amdgcn_mfma_f32_16x16x32_f16(a1f, b, acc[1][ni], 0, 0, 0);
            }
        }

        // ---- phase epilogue: attn partials + z stores ----
        float w1v[4], w2v[4];
#pragma unroll
        for (int ni = 0; ni < 4; ++ni) {
            int col = p * 64 + ni * 16 + l15;
            w1v[ni] = wattn[col];
            w2v[ni] = wattn[OUT_DIM + col];
        }
#pragma unroll
        for (int s = 0; s < 2; ++s) {
#pragma unroll
            for (int r = 0; r < 4; ++r) {
                float p1 = 0.f, p2 = 0.f;
#pragma unroll
                for (int ni = 0; ni < 4; ++ni) {
                    p1 += acc[s][ni][r] * w1v[ni];
                    p2 += acc[s][ni][r] * w2v[ni];
                }
#pragma unroll
                for (int o = 8; o; o >>= 1) {   // reduce across 16-lane col group
                    p1 += __shfl_xor(p1, o);
                    p2 += __shfl_xor(p2, o);
                }
                ps1[s][r] += p1;
                ps2[s][r] += p2;
                int row = m0 + s * 64 + w * 16 + quad * 4 + r;
                if (row < M) {
#pragma unroll
                    for (int ni = 0; ni < 4; ++ni)
                        zh[(size_t)row * OUT_DIM + p * 64 + ni * 16 + l15] =
                            (_Float16)acc[s][ni][r];
                }
            }
        }
    }

    // ---- final a1/a2 store (both col-halves combined) ----
    if (l15 == 0) {
#pragma unroll
        for (int s = 0; s < 2; ++s) {
#pragma unroll
            for (int r = 0; r < 4; ++r) {
                int row = m0 + s * 64 + w * 16 + quad * 4 + r;
                if (row < M) { a1[row] = ps1[s][r]; a2[row] = ps2[s][r]; }
            }
        }
    }
}

// --- K2: per-dst score + softmax + weighted aggregation (one wave per dst) --
// Scores computed here: e = lrelu(a1[src] + a2[w]); a2[w] is wave-uniform, a1
// is a 400KB L2-resident gather. cnt/slot/a2 loads issue in parallel (slots
// read unconditionally with clamped src so poison garbage is harmless).
// Quad-per-edge z gather: each quad owns one edge of an 8-edge flight; each
// lane loads 16B (8 f16 cols). Wave-uniform skip of the 2nd flight-half in
// the tail iteration avoids ~20% wasted row loads at Poisson(10) degrees.
__global__ __launch_bounds__(256) void agg_kernel(const _Float16* __restrict__ zh,
                                                  const int* __restrict__ cnt,
                                                  const int* __restrict__ bucket,
                                                  const float* __restrict__ a1,
                                                  const float* __restrict__ a2,
                                                  float* __restrict__ out,
                                                  int NW, int N) {
    const int lane = threadIdx.x & 63;
    const int w = blockIdx.x * 4 + (threadIdx.x >> 6);
    if (w >= NW) return;
    const int quad = lane >> 4;
    const int l15  = lane & 15;

    int deg = cnt[w];
    if (deg > CAP) deg = CAP;
    float a2w = a2[w];
    int raw = bucket[(size_t)w * CAP + lane];          // unconditional (in-bounds)
    int se  = ((unsigned)raw < (unsigned)N) ? raw : 0; // clamp poison garbage

    float x = a1[se] + a2w;
    float e = x > 0.f ? x : 0.01f * x;                 // leaky_relu(0.01)
    if (e == 0.f) e = -1000.f;                         // DGL zero-mask emulation
    float ev = (lane < deg) ? e : -INFINITY;

    float mx = ev;
#pragma unroll
    for (int o = 32; o; o >>= 1) mx = fmaxf(mx, __shfl_xor(mx, o));
    float ex = (lane < deg) ? __expf(ev - mx) : 0.f;
    float ssum = ex;
#pragma unroll
    for (int o = 32; o; o >>= 1) ssum += __shfl_xor(ssum, o);
    float al = (deg > 0) ? ex * (1.0f / ssum) : 0.f;   // per-lane alpha

    float acc[8] = {0.f, 0.f, 0.f, 0.f, 0.f, 0.f, 0.f, 0.f};
    for (int j = 0; j < deg; j += 8) {
        int i0 = j + quad;
        int c0 = (i0 < 63) ? i0 : 63;
        float w0 = __shfl(al, c0); if (i0 >= deg) w0 = 0.f;
        int   r0 = __shfl(se, c0);
        half8_t z0 = *(const half8_t*)(zh + (size_t)r0 * OUT_DIM + l15 * 8);
        if (j + 4 < deg) {               // wave-uniform: 2nd flight-half live?
            int i1 = i0 + 4;
            int c1 = (i1 < 63) ? i1 : 63;
            float w1 = __shfl(al, c1); if (i1 >= deg) w1 = 0.f;
            int   r1 = __shfl(se, c1);
            half8_t z1 = *(const half8_t*)(zh + (size_t)r1 * OUT_DIM + l15 * 8);
#pragma unroll
            for (int k = 0; k < 8; ++k) acc[k] += w0 * (float)z0[k] + w1 * (float)z1[k];
        } else {
#pragma unroll
            for (int k = 0; k < 8; ++k) acc[k] += w0 * (float)z0[k];
        }
    }
    // merge the 4 quads' partial sums (each holds all 8 cols, 1/4 of edges)
#pragma unroll
    for (int k = 0; k < 8; ++k) {
        acc[k] += __shfl_xor(acc[k], 16);
        acc[k] += __shfl_xor(acc[k], 32);
    }
    if (quad == 0) {   // 16 lanes x 32B = full 512B row (zeros if deg==0)
        float4 lo = {acc[0], acc[1], acc[2], acc[3]};
        float4 hi = {acc[4], acc[5], acc[6], acc[7]};
        float* op = out + (size_t)w * OUT_DIM + l15 * 8;
        *(float4*)op       = lo;
        *(float4*)(op + 4) = hi;
    }
}

// ---------------------------------------------------------------------------
extern "C" void kernel_launch(void* const* d_in, const int* in_sizes, int n_in,
                              void* d_out, int out_size, void* d_ws, size_t ws_size,
                              hipStream_t stream) {
    const float* h     = (const float*)d_in[0];
    const int*   src   = (const int*)d_in[1];
    const int*   dst   = (const int*)d_in[2];
    const float* wfc   = (const float*)d_in[3];
    const float* wattn = (const float*)d_in[4];
    float*       out   = (float*)d_out;

    const int N  = in_sizes[0] / IN_DIM;   // 100000
    const int E  = in_sizes[1];            // 500000
    const int NW = out_size / OUT_DIM;     // 50000
    const int nb = (NW + 255) / 256;       // 196 blocks (covers NW and 4096)
    const int GB = (N + 127) / 128;        // 782 gemm blocks
    const int SB = (E + 1023) / 1024;      // 489 scatter blocks (4 edges/thr)

    // workspace layout
    _Float16* zh = (_Float16*)d_ws;                      // N*128 f16   (25.6 MB)
    _Float16* wh = zh + (size_t)N * OUT_DIM;             // 256*128 f16 (swizzled)
    float* a1    = (float*)(wh + IN_DIM * OUT_DIM);      // N
    float* a2    = a1 + N;                               // N
    int*   cnt   = (int*)(a2 + N);                       // NW
    int*   bucket = cnt + NW;                            // NW*CAP ints (12.8 MB)

    wconv_kernel<<<nb, 256, 0, stream>>>(wfc, wh, cnt, NW);
    gemm_scatter_kernel<<<GB + SB, 256, 0, stream>>>(h, wh, wattn, zh, a1, a2, N, GB,
                                                     src, dst, cnt, bucket, E);
    agg_kernel<<<(NW + 3) / 4, 256, 0, stream>>>(zh, cnt, bucket, a1, a2, out, NW, N);
}

// Round 4
// 228.809 us; speedup vs baseline: 1.0773x; 1.0773x over previous
//
#include <hip/hip_runtime.h>
#include <cstddef>
#include <cmath>

// ---------------------------------------------------------------------------
// SWGAT layer:
//   z = h @ W_fc.T                       [N,128]
//   e = leaky_relu(a1[src] + a2[dst]);  e==0 -> -1000
//   segment softmax over dst, out[w] = sum alpha * z[src]
// R10: R9's col-split regressed (FETCH 52.8->115.5MB: A re-read NOT L3-held,
//      W staging doubled). Revert to R8 gemm geometry (256-row tile, full
//      64KB B LDS). Real R8 bottleneck: 977 scatter blocks QUEUED BEHIND 391
//      gemm blocks (2 blk/CU slots) -> ~40us serial atomic-latency tail with
//      near-zero utilization (matches the 3%/5%/33% counters). Now: scatter
//      first, 96 blocks (487 total <= 512 slots, all co-resident at t=0),
//      depth-2 atomic pipeline in scatter, depth-2 A prefetch in gemm K-loop,
//      wconv fused into gemm staging (wfc read f32->cvt->swizzled ds_write),
//      cnt zeroed by memset. Pipeline: memset + fused + agg.
// ---------------------------------------------------------------------------

#define IN_DIM  256
#define OUT_DIM 128
#define CAP     64      // max edges kept per dst (Poisson(10) => max deg ~30)

typedef _Float16 half2_t __attribute__((ext_vector_type(2)));
typedef _Float16 half8_t __attribute__((ext_vector_type(8)));
typedef float    f32x4   __attribute__((ext_vector_type(4)));

// --- K1: fused scatter + gemm dispatch --------------------------------------
// Blocks [0, SB): scatter. Grid-stride ~10 edges/thread, depth-2 software
//   pipeline so successive atomicAdds stay in flight (the bucket store of
//   edge k waits on its atomic AFTER edge k+1's atomic has issued).
// Blocks [SB, SB+GB): gemm. 512 thr = 8 waves, tile 256 rows x 128 cols.
//   B staged by reading wfc fp32 (L2-hot, 128KB), converting to f16 and
//   ds_write-ing swizzled granules (wconv fused; granule g = n*32+(kb^(n&7))
//   holds W[n][kb*8..+7]). Wave w owns rows {w*16..+15},{128+w*16..+15}.
//   K-loop: depth-2 A prefetch straight from global (32B/lane), one barrier.
__global__ __launch_bounds__(512, 4) void gemm_scatter_kernel(
        const float* __restrict__ h, const float* __restrict__ wfc,
        const float* __restrict__ wattn, _Float16* __restrict__ zh,
        float* __restrict__ a1, float* __restrict__ a2, int M, int SB,
        const int* __restrict__ src, const int* __restrict__ dst,
        int* __restrict__ cnt, int* __restrict__ bucket, int E) {
    __shared__ _Float16 Bs[IN_DIM * OUT_DIM];   // 64 KB

    const int t = threadIdx.x;

    if (blockIdx.x < SB) {
        // ---- scatter block: depth-2 atomic pipeline ----
        const int stride = SB * 512;
        int i = blockIdx.x * 512 + t;
        int s0 = 0, d0 = 0, p0 = CAP;
        bool v0 = (i < E);
        if (v0) {
            s0 = src[i]; d0 = dst[i];
            p0 = atomicAdd(&cnt[d0], 1);
        }
        for (int j = i + stride; ; j += stride) {
            bool v1 = (j < E);
            int s1 = 0, d1 = 0, p1 = CAP;
            if (v1) {                         // next edge's atomic issues...
                s1 = src[j]; d1 = dst[j];
                p1 = atomicAdd(&cnt[d1], 1);
            }
            if (v0 && p0 < CAP)               // ...before this one's store waits
                bucket[(size_t)d0 * CAP + p0] = s0;
            if (!v1) break;
            s0 = s1; d0 = d1; p0 = p1; v0 = true;
        }
        return;
    }

    // ---- gemm block ----
    const int lane = t & 63;
    const int w    = t >> 6;          // 0..7
    const int quad = lane >> 4;       // 0..3
    const int l15  = lane & 15;
    const int m0   = (blockIdx.x - SB) * 256;

    // stage B: read wfc fp32, convert, swizzled ds_write (wconv fused)
#pragma unroll
    for (int i = 0; i < 8; ++i) {
        int idx = t + i * 512;        // granule 0..4095
        int n   = idx >> 5;
        int kb  = idx & 31;
        const float* p = wfc + (size_t)n * IN_DIM + kb * 8;
        float4 q0 = *(const float4*)p;
        float4 q1 = *(const float4*)(p + 4);
        half8_t hv = {(_Float16)q0.x, (_Float16)q0.y, (_Float16)q0.z, (_Float16)q0.w,
                      (_Float16)q1.x, (_Float16)q1.y, (_Float16)q1.z, (_Float16)q1.w};
        *(half8_t*)&Bs[(size_t)(n * 32 + (kb ^ (n & 7))) * 8] = hv;
    }
    __syncthreads();   // the ONLY block-wide barrier

    // lane's two A rows (clamped; OOB rows computed but never stored)
    const int lrow0 = w * 16 + l15;
    const int lrow1 = 128 + w * 16 + l15;
    const int g0 = (m0 + lrow0 < M) ? (m0 + lrow0) : (M - 1);
    const int g1 = (m0 + lrow1 < M) ? (m0 + lrow1) : (M - 1);
    const float* arow0 = h + (size_t)g0 * IN_DIM + quad * 8;
    const float* arow1 = h + (size_t)g1 * IN_DIM + quad * 8;

    f32x4 acc[2][8] = {};   // [row-set][ni]

    // depth-2 A prefetch: kc+1's loads are in flight during kc's MFMAs
    float4 nu0 = *(const float4*)(arow0);
    float4 nu1 = *(const float4*)(arow0 + 4);
    float4 nv0 = *(const float4*)(arow1);
    float4 nv1 = *(const float4*)(arow1 + 4);
#pragma unroll
    for (int kc = 0; kc < 8; ++kc) {
        float4 cu0 = nu0, cu1 = nu1, cv0 = nv0, cv1 = nv1;
        if (kc < 7) {
            nu0 = *(const float4*)(arow0 + (kc + 1) * 32);
            nu1 = *(const float4*)(arow0 + (kc + 1) * 32 + 4);
            nv0 = *(const float4*)(arow1 + (kc + 1) * 32);
            nv1 = *(const float4*)(arow1 + (kc + 1) * 32 + 4);
        }
        half8_t a0 = {(_Float16)cu0.x, (_Float16)cu0.y, (_Float16)cu0.z, (_Float16)cu0.w,
                      (_Float16)cu1.x, (_Float16)cu1.y, (_Float16)cu1.z, (_Float16)cu1.w};
        half8_t a1f = {(_Float16)cv0.x, (_Float16)cv0.y, (_Float16)cv0.z, (_Float16)cv0.w,
                       (_Float16)cv1.x, (_Float16)cv1.y, (_Float16)cv1.z, (_Float16)cv1.w};
#pragma unroll
        for (int ni = 0; ni < 8; ++ni) {
            int n = ni * 16 + l15;
            int g = (kc * 4 + quad) ^ (n & 7);
            half8_t b = *(const half8_t*)&Bs[(size_t)(n * 32 + g) * 8];
            acc[0][ni] = __builtin_amdgcn_mfma_f32_16x16x32_f16(a0,  b, acc[0][ni], 0, 0, 0);
            acc[1][ni] = __builtin_amdgcn_mfma_f32_16x16x32_f16(a1f, b, acc[1][ni], 0, 0, 0);
        }
    }

    // ---- fused a1/a2 + z stores (C/D layout col=l15, row=quad*4+r) ----
    float w1v[8], w2v[8];
#pragma unroll
    for (int ni = 0; ni < 8; ++ni) {
        int col = ni * 16 + l15;
        w1v[ni] = wattn[col];
        w2v[ni] = wattn[OUT_DIM + col];
    }
#pragma unroll
    for (int s = 0; s < 2; ++s) {
#pragma unroll
        for (int r = 0; r < 4; ++r) {
            float p1 = 0.f, p2 = 0.f;
#pragma unroll
            for (int ni = 0; ni < 8; ++ni) {
                p1 += acc[s][ni][r] * w1v[ni];
                p2 += acc[s][ni][r] * w2v[ni];
            }
#pragma unroll
            for (int o = 8; o; o >>= 1) {   // reduce across the 16-lane col group
                p1 += __shfl_xor(p1, o);
                p2 += __shfl_xor(p2, o);
            }
            int row = m0 + s * 128 + w * 16 + quad * 4 + r;
            if (row < M) {
                if (l15 == 0) { a1[row] = p1; a2[row] = p2; }
#pragma unroll
                for (int ni = 0; ni < 8; ++ni)
                    zh[(size_t)row * OUT_DIM + ni * 16 + l15] = (_Float16)acc[s][ni][r];
            }
        }
    }
}

// --- K2: per-dst score + softmax + weighted aggregation (one wave per dst) --
// Scores computed here: e = lrelu(a1[src] + a2[w]); a2[w] is wave-uniform, a1
// is a 400KB L2-resident gather. cnt/slot/a2 loads issue in parallel (slots
// read unconditionally with clamped src so poison garbage is harmless).
// Quad-per-edge z gather: each quad owns one edge of an 8-edge flight; each
// lane loads 16B (8 f16 cols). Wave-uniform skip of the 2nd flight-half in
// the tail iteration avoids ~20% wasted row loads at Poisson(10) degrees.
__global__ __launch_bounds__(256) void agg_kernel(const _Float16* __restrict__ zh,
                                                  const int* __restrict__ cnt,
                                                  const int* __restrict__ bucket,
                                                  const float* __restrict__ a1,
                                                  const float* __restrict__ a2,
                                                  float* __restrict__ out,
                                                  int NW, int N) {
    const int lane = threadIdx.x & 63;
    const int w = blockIdx.x * 4 + (threadIdx.x >> 6);
    if (w >= NW) return;
    const int quad = lane >> 4;
    const int l15  = lane & 15;

    int deg = cnt[w];
    if (deg > CAP) deg = CAP;
    float a2w = a2[w];
    int raw = bucket[(size_t)w * CAP + lane];          // unconditional (in-bounds)
    int se  = ((unsigned)raw < (unsigned)N) ? raw : 0; // clamp poison garbage

    float x = a1[se] + a2w;
    float e = x > 0.f ? x : 0.01f * x;                 // leaky_relu(0.01)
    if (e == 0.f) e = -1000.f;                         // DGL zero-mask emulation
    float ev = (lane < deg) ? e : -INFINITY;

    float mx = ev;
#pragma unroll
    for (int o = 32; o; o >>= 1) mx = fmaxf(mx, __shfl_xor(mx, o));
    float ex = (lane < deg) ? __expf(ev - mx) : 0.f;
    float ssum = ex;
#pragma unroll
    for (int o = 32; o; o >>= 1) ssum += __shfl_xor(ssum, o);
    float al = (deg > 0) ? ex * (1.0f / ssum) : 0.f;   // per-lane alpha

    float acc[8] = {0.f, 0.f, 0.f, 0.f, 0.f, 0.f, 0.f, 0.f};
    for (int j = 0; j < deg; j += 8) {
        int i0 = j + quad;
        int c0 = (i0 < 63) ? i0 : 63;
        float w0 = __shfl(al, c0); if (i0 >= deg) w0 = 0.f;
        int   r0 = __shfl(se, c0);
        half8_t z0 = *(const half8_t*)(zh + (size_t)r0 * OUT_DIM + l15 * 8);
        if (j + 4 < deg) {               // wave-uniform: 2nd flight-half live?
            int i1 = i0 + 4;
            int c1 = (i1 < 63) ? i1 : 63;
            float w1 = __shfl(al, c1); if (i1 >= deg) w1 = 0.f;
            int   r1 = __shfl(se, c1);
            half8_t z1 = *(const half8_t*)(zh + (size_t)r1 * OUT_DIM + l15 * 8);
#pragma unroll
            for (int k = 0; k < 8; ++k) acc[k] += w0 * (float)z0[k] + w1 * (float)z1[k];
        } else {
#pragma unroll
            for (int k = 0; k < 8; ++k) acc[k] += w0 * (float)z0[k];
        }
    }
    // merge the 4 quads' partial sums (each holds all 8 cols, 1/4 of edges)
#pragma unroll
    for (int k = 0; k < 8; ++k) {
        acc[k] += __shfl_xor(acc[k], 16);
        acc[k] += __shfl_xor(acc[k], 32);
    }
    if (quad == 0) {   // 16 lanes x 32B = full 512B row (zeros if deg==0)
        float4 lo = {acc[0], acc[1], acc[2], acc[3]};
        float4 hi = {acc[4], acc[5], acc[6], acc[7]};
        float* op = out + (size_t)w * OUT_DIM + l15 * 8;
        *(float4*)op       = lo;
        *(float4*)(op + 4) = hi;
    }
}

// ---------------------------------------------------------------------------
extern "C" void kernel_launch(void* const* d_in, const int* in_sizes, int n_in,
                              void* d_out, int out_size, void* d_ws, size_t ws_size,
                              hipStream_t stream) {
    const float* h     = (const float*)d_in[0];
    const int*   src   = (const int*)d_in[1];
    const int*   dst   = (const int*)d_in[2];
    const float* wfc   = (const float*)d_in[3];
    const float* wattn = (const float*)d_in[4];
    float*       out   = (float*)d_out;

    const int N  = in_sizes[0] / IN_DIM;   // 100000
    const int E  = in_sizes[1];            // 500000
    const int NW = out_size / OUT_DIM;     // 50000
    const int GB = (N + 255) / 256;        // 391 gemm blocks
    const int SB = 96;                     // scatter blocks (96+391=487 <= 512 slots)

    // workspace layout
    _Float16* zh = (_Float16*)d_ws;                      // N*128 f16   (25.6 MB)
    float* a1    = (float*)(zh + (size_t)N * OUT_DIM);   // N
    float* a2    = a1 + N;                               // N
    int*   cnt   = (int*)(a2 + N);                       // NW
    int*   bucket = cnt + NW;                            // NW*CAP ints (12.8 MB)

    hipMemsetAsync(cnt, 0, (size_t)NW * sizeof(int), stream);
    gemm_scatter_kernel<<<SB + GB, 512, 0, stream>>>(h, wfc, wattn, zh, a1, a2, N, SB,
                                                     src, dst, cnt, bucket, E);
    agg_kernel<<<(NW + 3) / 4, 256, 0, stream>>>(zh, cnt, bucket, a1, a2, out, NW, N);
}